// Round 13
// baseline (165.766 us; speedup 1.0000x reference)
//
#include <hip/hip_runtime.h>
#include <stdint.h>

#define BS 8
#define NN 256
#define GD 64
#define ND 64
#define ED 32

typedef __bf16 bf16x8 __attribute__((ext_vector_type(8)));
typedef float f32x4 __attribute__((ext_vector_type(4)));

// ---------------------------------------------------------------------------
// K1: vj[b,n,o] = V[b,n,:]@Wa_vj[:,o] ; vi[b,n,o] = V[b,n,:]@Wa_vi[:,o]
//     up[b,o]   = u[b,:]@Wa_u[:,o] + b_A[o]
// Also zeroes colsum/vagg/aagg (ws re-poisoned 0xAA before every call).
// grid = 64 blocks x 256 thr; 32 V-rows per block; W_vj|W_vi staged in LDS
// ---------------------------------------------------------------------------
__global__ __launch_bounds__(256) void k1_proj(
        const float* __restrict__ u, const float* __restrict__ V,
        const float* __restrict__ W_A, const float* __restrict__ b_A,
        float* __restrict__ vj, float* __restrict__ vi, float* __restrict__ up,
        float* __restrict__ colsum) {
    __shared__ float W2[2 * ND][ED];   // 16KB: W_A rows ED..ED+127
    __shared__ float Vt[32][ND];       // 8KB
    int t   = threadIdx.x;
    int blk = blockIdx.x;
    int bn0 = blk * 32;
    // zero colsum (65536f) + vagg (512f) + aagg (256f)
    {
        float4 z4 = make_float4(0.f, 0.f, 0.f, 0.f);
        ((float4*)colsum)[blk * 256 + t] = z4;
        if (blk == 0 && t < 192) ((float4*)(colsum + BS * NN * ED))[t] = z4;
    }
    {
        const float4* src = (const float4*)(W_A + ED * ED);
        float4* dst = (float4*)&W2[0][0];
#pragma unroll
        for (int r = 0; r < 4; ++r) dst[r * 256 + t] = src[r * 256 + t];
    }
    {
        const float4* src = (const float4*)(V + (size_t)bn0 * ND);
        float4* dst = (float4*)&Vt[0][0];
        dst[t]       = src[t];
        dst[256 + t] = src[256 + t];
    }
    __syncthreads();
    int rq  = t >> 6;          // 0..3
    int oo  = t & 63;
    int mat = oo >> 5;         // 0 = vj, 1 = vi
    int o   = oo & 31;
#pragma unroll 2
    for (int p = 0; p < 8; ++p) {
        int rl = p * 4 + rq;
        int bn = bn0 + rl;
        float d0 = 0.f, d1 = 0.f, d2 = 0.f, d3 = 0.f;
#pragma unroll
        for (int k = 0; k < ND; k += 4) {
            d0 = fmaf(Vt[rl][k + 0], W2[mat * ND + k + 0][o], d0);
            d1 = fmaf(Vt[rl][k + 1], W2[mat * ND + k + 1][o], d1);
            d2 = fmaf(Vt[rl][k + 2], W2[mat * ND + k + 2][o], d2);
            d3 = fmaf(Vt[rl][k + 3], W2[mat * ND + k + 3][o], d3);
        }
        float acc = (d0 + d1) + (d2 + d3);
        if (mat == 0) vj[bn * ED + o] = acc;
        else          vi[bn * ED + o] = acc;
    }
    if (blk < 8 && t < 32) {
        float a2 = b_A[t];
#pragma unroll 8
        for (int k = 0; k < GD; ++k)
            a2 = fmaf(u[blk * GD + k], W_A[(ED + 2 * ND + k) * ED + t], a2);
        up[blk * ED + t] = a2;
    }
}

// ---------------------------------------------------------------------------
// K2 (MFMA): per block, GEMM [M=128 rows = 16i x 8j] x [K=32] x [N=32]
// using mfma_f32_16x16x32_bf16. A-fragments load DIRECTLY from global
// (each element read once, no LDS broadcast redundancy), cvt f32->bf16 in
// regs. C layout (m89-verified): col = lane&15, row = (lane>>4)*4 + reg.
// Wave wv handles M-tiles 2wv, 2wv+1 (ii = 4wv .. 4wv+3), both N-tiles.
// colsum via shfl_xor(32) fold + atomics. grid = 4096 x 256.
// ---------------------------------------------------------------------------
__global__ __launch_bounds__(256) void k2_main(
        const float* __restrict__ A, const float* __restrict__ W_A,
        const float* __restrict__ vj, const float* __restrict__ vi,
        const float* __restrict__ up,
        float* __restrict__ Aprime, float* __restrict__ colsum) {
    __shared__ float cjt[8][ED + 1];    // vj+up for block's 8 j (padded)
    __shared__ float vit[16][ED + 1];   // vi for block's 16 i (padded)
    int bid = blockIdx.x;
    int b   = bid >> 9;
    int it  = (bid >> 5) & 15;
    int jc  = bid & 31;
    int t    = threadIdx.x;
    int lane = t & 63;
    int wv   = t >> 6;
    int i0 = it * 16;
    int j0 = jc * 8;

    // stage cj and vi tiles (tiny)
    {
        int jl = t >> 5, o = t & 31;
        cjt[jl][o]     = vj[(b * NN + j0 + jl) * ED + o] + up[b * ED + o];
        vit[jl][o]     = vi[(b * NN + i0 + jl) * ED + o];
        vit[jl + 8][o] = vi[(b * NN + i0 + jl + 8) * ED + o];
    }

    int r    = lane & 15;      // A-row within 16-tile
    int kc   = lane >> 4;      // k-chunk (8 elems)
    int o0   = lane & 15;      // output col within N-tile
    int jl_r = r & 7;          // jloc of A-row
    int ih_r = r >> 3;         // ii-offset within M-tile

    // B fragments: B[k][col] = W_A[k*ED + o], k = kc*8+e
    bf16x8 bf0, bf1;
#pragma unroll
    for (int e = 0; e < 8; ++e) {
        bf0[e] = (__bf16)W_A[(kc * 8 + e) * ED + o0];
        bf1[e] = (__bf16)W_A[(kc * 8 + e) * ED + 16 + o0];
    }

    __syncthreads();

    float colA0[4] = {0.f, 0.f, 0.f, 0.f};
    float colA1[4] = {0.f, 0.f, 0.f, 0.f};

#pragma unroll
    for (int m = 0; m < 2; ++m) {
        int mt = wv * 2 + m;
        int ii = mt * 2 + ih_r;        // local i (0..15)
        const float* src =
            A + ((size_t)(b * NN + i0 + ii) * NN + (j0 + jl_r)) * ED + kc * 8;
        float4 f0 = *(const float4*)src;
        float4 f1 = *(const float4*)(src + 4);
        bf16x8 af;
        af[0] = (__bf16)f0.x; af[1] = (__bf16)f0.y;
        af[2] = (__bf16)f0.z; af[3] = (__bf16)f0.w;
        af[4] = (__bf16)f1.x; af[5] = (__bf16)f1.y;
        af[6] = (__bf16)f1.z; af[7] = (__bf16)f1.w;
        f32x4 acc0 = {0.f, 0.f, 0.f, 0.f};
        f32x4 acc1 = {0.f, 0.f, 0.f, 0.f};
        acc0 = __builtin_amdgcn_mfma_f32_16x16x32_bf16(af, bf0, acc0, 0, 0, 0);
        acc1 = __builtin_amdgcn_mfma_f32_16x16x32_bf16(af, bf1, acc1, 0, 0, 0);
#pragma unroll
        for (int q = 0; q < 4; ++q) {
            int rr   = (lane >> 4) * 4 + q;    // C-row within 16-tile
            int jloc = rr & 7;
            int iiq  = mt * 2 + (rr >> 3);     // local i
            float* dst =
                Aprime + ((size_t)(b * NN + i0 + iiq) * NN + (j0 + jloc)) * ED;
            float v0 = fmaxf(acc0[q] + cjt[jloc][o0] + vit[iiq][o0], 0.f);
            float v1 = fmaxf(acc1[q] + cjt[jloc][16 + o0] + vit[iiq][16 + o0], 0.f);
            __builtin_nontemporal_store(v0, dst + o0);
            __builtin_nontemporal_store(v1, dst + 16 + o0);
            colA0[q] += v0;
            colA1[q] += v1;
        }
    }
    // fold the two ii-halves: lane^32 has same (jloc, o), other ii-group
#pragma unroll
    for (int q = 0; q < 4; ++q) {
        colA0[q] += __shfl_xor(colA0[q], 32, 64);
        colA1[q] += __shfl_xor(colA1[q], 32, 64);
    }
    if (lane < 32) {
#pragma unroll
        for (int q = 0; q < 4; ++q) {
            int jl = (lane >> 4) * 4 + q;   // jloc 0..7
            atomicAdd(&colsum[(b * NN + j0 + jl) * ED + o0],      colA0[q]);
            atomicAdd(&colsum[(b * NN + j0 + jl) * ED + 16 + o0], colA1[q]);
        }
    }
}

// ---------------------------------------------------------------------------
// K3: V_prime[b,n,d] = relu([colsum/256, V, u] @ W_v + b_v)
// Also emits block-reduced vagg (sum Vprime rows) and aagg (sum colsum rows).
// grid = 128 blocks x 256 thr; 16 rows per block; W_v staged in LDS (40KB)
// ---------------------------------------------------------------------------
__global__ __launch_bounds__(256) void k3_vprime(
        const float* __restrict__ V, const float* __restrict__ u,
        const float* __restrict__ W_v, const float* __restrict__ b_v,
        const float* __restrict__ colsum, float* __restrict__ Vprime,
        float* __restrict__ vagg, float* __restrict__ aagg) {
    __shared__ float Wv[ED + ND + GD][ND];   // 160x64 = 40KB
    __shared__ float xv[16][ED + ND + GD + 1];
    __shared__ float vred[4][ND];
    __shared__ float ared[4][ED];
    int t = threadIdx.x;
    {
        const float4* src = (const float4*)W_v;
        float4* dst = (float4*)&Wv[0][0];
#pragma unroll
        for (int r = 0; r < 10; ++r) dst[r * 256 + t] = src[r * 256 + t];
    }
    int bn0 = blockIdx.x * 16;
    int b   = bn0 >> 8;
    int d  = t & 63;
    int rq = t >> 6;
#pragma unroll
    for (int p = 0; p < 4; ++p) {
        int rl = p * 4 + rq;
        int bn = bn0 + rl;
        if (d < 32) xv[rl][d] = colsum[bn * ED + d] * (1.f / 256.f);
        xv[rl][ED + d]      = V[(size_t)bn * ND + d];
        xv[rl][ED + ND + d] = u[b * GD + d];
    }
    __syncthreads();
    float vsum = 0.f;
#pragma unroll 2
    for (int p = 0; p < 4; ++p) {
        int rl = p * 4 + rq;
        float acc = b_v[d];
#pragma unroll 8
        for (int k = 0; k < ED + ND + GD; ++k)
            acc = fmaf(xv[rl][k], Wv[k][d], acc);
        acc = fmaxf(acc, 0.f);
        Vprime[(size_t)(bn0 + rl) * ND + d] = acc;
        vsum += acc;
    }
    vred[rq][d] = vsum;
    if (d < 32) {
        float asum = xv[rq][d] + xv[4 + rq][d] + xv[8 + rq][d] + xv[12 + rq][d];
        ared[rq][d] = asum;            // carries the 1/256 factor
    }
    __syncthreads();
    if (t < 64) {
        atomicAdd(&vagg[b * ND + t],
                  vred[0][t] + vred[1][t] + vred[2][t] + vred[3][t]);
    } else if (t < 96) {
        int o = t - 64;
        atomicAdd(&aagg[b * ED + o],
                  ared[0][o] + ared[1][o] + ared[2][o] + ared[3][o]);
    }
}

// ---------------------------------------------------------------------------
// K4: u_prime = relu([aagg/256, vagg/256, u] @ W_u + b_u). grid = 8 x 64 thr
// (aagg already carries 1/256 from k3; /256 more gives /65536 total.)
// ---------------------------------------------------------------------------
__global__ __launch_bounds__(64) void k4_uprime(
        const float* __restrict__ u,
        const float* __restrict__ W_u, const float* __restrict__ b_u,
        const float* __restrict__ vagg, const float* __restrict__ aagg,
        float* __restrict__ uprime) {
    int b = blockIdx.x;
    int t = threadIdx.x;       // 0..63
    __shared__ float xu[ED + ND + GD];
    if (t < 32) xu[t] = aagg[b * ED + t] * (1.f / 256.f);
    xu[ED + t]      = vagg[b * ND + t] * (1.f / 256.f);
    xu[ED + ND + t] = u[b * GD + t];
    __syncthreads();
    float acc = b_u[t];
#pragma unroll 8
    for (int k = 0; k < ED + ND + GD; ++k)
        acc = fmaf(xu[k], W_u[k * GD + t], acc);
    uprime[b * GD + t] = fmaxf(acc, 0.f);
}

// ---------------------------------------------------------------------------
extern "C" void kernel_launch(void* const* d_in, const int* in_sizes, int n_in,
                              void* d_out, int out_size, void* d_ws, size_t ws_size,
                              hipStream_t stream) {
    const float* u   = (const float*)d_in[0];
    const float* V   = (const float*)d_in[1];
    const float* A   = (const float*)d_in[2];
    const float* W_A = (const float*)d_in[3];
    const float* b_A = (const float*)d_in[4];
    const float* W_v = (const float*)d_in[5];
    const float* b_v = (const float*)d_in[6];
    const float* W_u = (const float*)d_in[7];
    const float* b_u = (const float*)d_in[8];

    float* out    = (float*)d_out;
    float* uprime = out;                           // 8*64
    float* Vprime = out + BS * GD;                 // 8*256*64
    float* Aprime = out + BS * GD + BS * NN * ND;  // 8*256*256*32

    float* ws     = (float*)d_ws;
    float* vj     = ws;                            // BS*NN*ED (65536 f)
    float* vi     = vj + BS * NN * ED;             // BS*NN*ED
    float* up     = vi + BS * NN * ED;             // BS*ED (256 f)
    float* colsum = up + BS * ED;                  // BS*NN*ED (65536 f)
    float* vagg   = colsum + BS * NN * ED;         // BS*ND (512 f)
    float* aagg   = vagg + BS * ND;                // BS*ED (256 f)

    hipLaunchKernelGGL(k1_proj, dim3(64), dim3(256), 0, stream,
                       u, V, W_A, b_A, vj, vi, up, colsum);
    hipLaunchKernelGGL(k2_main, dim3(4096), dim3(256), 0, stream,
                       A, W_A, vj, vi, up, Aprime, colsum);
    hipLaunchKernelGGL(k3_vprime, dim3(128), dim3(256), 0, stream,
                       V, u, W_v, b_v, colsum, Vprime, vagg, aagg);
    hipLaunchKernelGGL(k4_uprime, dim3(BS), dim3(64), 0, stream,
                       u, W_u, b_u, vagg, aagg, uprime);
}